// Round 2
// baseline (221.575 us; speedup 1.0000x reference)
//
#include <hip/hip_runtime.h>
#include <stdint.h>

#define BATCH 16
#define HH 1024
#define WW 1024
#define TH 32                 // output rows per block
#define HALO 4
#define ROWS (TH + 2*HALO)    // 40 staged rows
#define WORDS (WW/64)         // 16 uint64 words per row
#define NTHREADS 256
#define NWAVES (NTHREADS/64)

__global__ __launch_bounds__(NTHREADS) void circle_mse_kernel(
    const float* __restrict__ y_pred,
    const float* __restrict__ y_true,
    float* __restrict__ out)
{
    __shared__ unsigned long long bits0[ROWS][WORDS];  // packed y_true (kept)
    __shared__ unsigned long long cur[ROWS][WORDS];    // erosion state
    __shared__ unsigned long long tmp[ROWS][WORDS];    // h-pass scratch
    __shared__ unsigned long long E[4][TH][WORDS];     // e1..e4 bit-planes
    __shared__ float wavesum[NWAVES];

    const int tid  = threadIdx.x;
    const int lane = tid & 63;
    const int wave = tid >> 6;

    const int im = blockIdx.x / (HH / TH);
    const int rb = blockIdx.x % (HH / TH);
    const int r0 = rb * TH - HALO;  // global row of staged row 0

    const float* yt = y_true + (size_t)im * HH * WW;
    const float* yp = y_pred + (size_t)im * HH * WW;

    // ---- pack y_true tile into bitmasks (zero outside image = zero-pad) ----
    #pragma unroll 4
    for (int p = wave; p < ROWS * WORDS; p += NWAVES) {
        int row  = p >> 4;            // / WORDS
        int word = p & (WORDS - 1);
        int gr   = r0 + row;
        unsigned long long m = 0ull;
        if (gr >= 0 && gr < HH) {     // wave-uniform branch
            float v = yt[(size_t)gr * WW + word * 64 + lane];
            m = __ballot(v != 0.0f);
        }
        if (lane == 0) { bits0[row][word] = m; cur[row][word] = m; }
    }
    __syncthreads();

    // ---- 4 iterated 3x3 binary erosions (AND of shifts), shrinking halo ----
    for (int k = 1; k <= 4; ++k) {
        // horizontal: rows [k-1, ROWS-(k-1))
        int lo = k - 1, hi = ROWS - (k - 1);
        for (int p = tid; p < (hi - lo) * WORDS; p += NTHREADS) {
            int row  = lo + (p >> 4);
            int word = p & (WORDS - 1);
            unsigned long long m = cur[row][word];
            unsigned long long l = (word > 0)         ? cur[row][word - 1] : 0ull;
            unsigned long long r = (word < WORDS - 1) ? cur[row][word + 1] : 0ull;
            tmp[row][word] = m & ((m << 1) | (l >> 63)) & ((m >> 1) | (r << 63));
        }
        __syncthreads();
        // vertical: rows [k, ROWS-k)
        lo = k; hi = ROWS - k;
        for (int p = tid; p < (hi - lo) * WORDS; p += NTHREADS) {
            int row  = lo + (p >> 4);
            int word = p & (WORDS - 1);
            unsigned long long res = tmp[row - 1][word] & tmp[row][word] & tmp[row + 1][word];
            cur[row][word] = res;
            if (row >= HALO && row < HALO + TH) E[k - 1][row - HALO][word] = res;
        }
        __syncthreads();
    }

    // ---- fused weighted-MSE + reduction (float4 y_pred loads) ----
    // thread tid handles float4 index q=tid of each row: columns 4q..4q+3
    const int word = tid >> 4;          // (4*tid)/64
    const int bsh  = (tid & 15) * 4;    // bit position of column 4q within word
    float lsum = 0.0f;
    for (int row = 0; row < TH; ++row) {
        int gr = r0 + HALO + row;
        float4 pv = *reinterpret_cast<const float4*>(&yp[(size_t)gr * WW + tid * 4]);
        unsigned int y4 = (unsigned int)((bits0[row + HALO][word] >> bsh) & 0xFull);
        unsigned int n1 = (unsigned int)((E[0][row][word] >> bsh) & 0xFull);
        unsigned int n2 = (unsigned int)((E[1][row][word] >> bsh) & 0xFull);
        unsigned int n3 = (unsigned int)((E[2][row][word] >> bsh) & 0xFull);
        unsigned int n4 = (unsigned int)((E[3][row][word] >> bsh) & 0xFull);
        float pvals[4] = {pv.x, pv.y, pv.z, pv.w};
        #pragma unroll
        for (int j = 0; j < 4; ++j) {
            unsigned int y = (y4 >> j) & 1u;
            unsigned int c = y + ((n1 >> j) & 1u) + ((n2 >> j) & 1u)
                               + ((n3 >> j) & 1u) + ((n4 >> j) & 1u);
            float w = (c == 0u || c == 5u) ? 0.8f : (0.3f + 0.1f * (float)c);
            float d = pvals[j] - (float)y;
            lsum += d * d * w;
        }
    }

    // wave reduce (64 lanes)
    for (int off = 32; off > 0; off >>= 1)
        lsum += __shfl_down(lsum, off, 64);
    if (lane == 0) wavesum[wave] = lsum;
    __syncthreads();
    if (tid == 0) {
        float s = 0.0f;
        for (int wv = 0; wv < NWAVES; ++wv) s += wavesum[wv];
        atomicAdd(&out[im], s * (1.0f / (float)(HH * WW)));
        atomicAdd(&out[BATCH], s * (1.0f / ((float)BATCH * (float)(HH * WW))));
    }
}

extern "C" void kernel_launch(void* const* d_in, const int* in_sizes, int n_in,
                              void* d_out, int out_size, void* d_ws, size_t ws_size,
                              hipStream_t stream) {
    const float* y_pred = (const float*)d_in[0];
    const float* y_true = (const float*)d_in[1];
    float* out = (float*)d_out;

    // harness re-poisons d_out to 0xAA before every timed launch
    hipMemsetAsync(d_out, 0, (size_t)out_size * sizeof(float), stream);

    dim3 grid(BATCH * (HH / TH));
    circle_mse_kernel<<<grid, NTHREADS, 0, stream>>>(y_pred, y_true, out);
}

// Round 3
// 181.821 us; speedup vs baseline: 1.2186x; 1.2186x over previous
//
#include <hip/hip_runtime.h>
#include <stdint.h>

#define BATCH 16
#define HH 1024
#define WW 1024
#define TH 8                  // output rows per block (small => 2048 blocks => full occupancy)
#define HALO 4
#define ROWS (TH + 2*HALO)    // 16 staged rows
#define WORDS (WW/64)         // 16 uint64 words per row
#define NTHREADS 256
#define NWAVES (NTHREADS/64)

__global__ __launch_bounds__(NTHREADS) void circle_mse_kernel(
    const float* __restrict__ y_pred,
    const float* __restrict__ y_true,
    float* __restrict__ out)
{
    __shared__ unsigned long long bits0[ROWS][WORDS];  // packed y_true (kept)
    __shared__ unsigned long long cur[ROWS][WORDS];    // erosion state
    __shared__ unsigned long long tmp[ROWS][WORDS];    // h-pass scratch
    __shared__ unsigned long long E[4][TH][WORDS];     // e1..e4 bit-planes
    __shared__ float wavesum[NWAVES];

    const int tid  = threadIdx.x;
    const int lane = tid & 63;
    const int wave = tid >> 6;

    const int im = blockIdx.x / (HH / TH);
    const int rb = blockIdx.x % (HH / TH);
    const int r0 = rb * TH - HALO;  // global row of staged row 0

    const float* yt = y_true + (size_t)im * HH * WW;
    const float* yp = y_pred + (size_t)im * HH * WW;

    // ---- pack y_true tile into bitmasks (zero outside image = zero-pad) ----
    // ROWS*WORDS = 256 items, 4 waves => 64 iters/wave; unroll for outstanding loads
    #pragma unroll 8
    for (int p = wave; p < ROWS * WORDS; p += NWAVES) {
        int row  = p >> 4;            // / WORDS
        int word = p & (WORDS - 1);
        int gr   = r0 + row;
        unsigned long long m = 0ull;
        if (gr >= 0 && gr < HH) {     // wave-uniform branch
            float v = yt[(size_t)gr * WW + word * 64 + lane];
            m = __ballot(v != 0.0f);
        }
        if (lane == 0) { bits0[row][word] = m; cur[row][word] = m; }
    }
    __syncthreads();

    // ---- 4 iterated 3x3 binary erosions (AND of shifts), shrinking halo ----
    for (int k = 1; k <= 4; ++k) {
        // horizontal: rows [k-1, ROWS-(k-1))
        int lo = k - 1, hi = ROWS - (k - 1);
        for (int p = tid; p < (hi - lo) * WORDS; p += NTHREADS) {
            int row  = lo + (p >> 4);
            int word = p & (WORDS - 1);
            unsigned long long m = cur[row][word];
            unsigned long long l = (word > 0)         ? cur[row][word - 1] : 0ull;
            unsigned long long r = (word < WORDS - 1) ? cur[row][word + 1] : 0ull;
            tmp[row][word] = m & ((m << 1) | (l >> 63)) & ((m >> 1) | (r << 63));
        }
        __syncthreads();
        // vertical: rows [k, ROWS-k)
        lo = k; hi = ROWS - k;
        for (int p = tid; p < (hi - lo) * WORDS; p += NTHREADS) {
            int row  = lo + (p >> 4);
            int word = p & (WORDS - 1);
            unsigned long long res = tmp[row - 1][word] & tmp[row][word] & tmp[row + 1][word];
            cur[row][word] = res;
            if (row >= HALO && row < HALO + TH) E[k - 1][row - HALO][word] = res;
        }
        __syncthreads();
    }

    // ---- fused weighted-MSE + reduction (float4 y_pred loads) ----
    // thread tid handles float4 index q=tid of each row: columns 4q..4q+3
    const int word = tid >> 4;          // (4*tid)/64
    const int bsh  = (tid & 15) * 4;    // bit position of column 4q within word
    float lsum = 0.0f;
    #pragma unroll
    for (int row = 0; row < TH; ++row) {
        int gr = r0 + HALO + row;
        float4 pv = *reinterpret_cast<const float4*>(&yp[(size_t)gr * WW + tid * 4]);
        unsigned int y4 = (unsigned int)((bits0[row + HALO][word] >> bsh) & 0xFull);
        unsigned int n1 = (unsigned int)((E[0][row][word] >> bsh) & 0xFull);
        unsigned int n2 = (unsigned int)((E[1][row][word] >> bsh) & 0xFull);
        unsigned int n3 = (unsigned int)((E[2][row][word] >> bsh) & 0xFull);
        unsigned int n4 = (unsigned int)((E[3][row][word] >> bsh) & 0xFull);
        float pvals[4] = {pv.x, pv.y, pv.z, pv.w};
        #pragma unroll
        for (int j = 0; j < 4; ++j) {
            unsigned int y = (y4 >> j) & 1u;
            unsigned int c = y + ((n1 >> j) & 1u) + ((n2 >> j) & 1u)
                               + ((n3 >> j) & 1u) + ((n4 >> j) & 1u);
            float w = (c == 0u || c == 5u) ? 0.8f : (0.3f + 0.1f * (float)c);
            float d = pvals[j] - (float)y;
            lsum += d * d * w;
        }
    }

    // wave reduce (64 lanes)
    for (int off = 32; off > 0; off >>= 1)
        lsum += __shfl_down(lsum, off, 64);
    if (lane == 0) wavesum[wave] = lsum;
    __syncthreads();
    if (tid == 0) {
        float s = 0.0f;
        for (int wv = 0; wv < NWAVES; ++wv) s += wavesum[wv];
        atomicAdd(&out[im], s * (1.0f / (float)(HH * WW)));
        atomicAdd(&out[BATCH], s * (1.0f / ((float)BATCH * (float)(HH * WW))));
    }
}

extern "C" void kernel_launch(void* const* d_in, const int* in_sizes, int n_in,
                              void* d_out, int out_size, void* d_ws, size_t ws_size,
                              hipStream_t stream) {
    const float* y_pred = (const float*)d_in[0];
    const float* y_true = (const float*)d_in[1];
    float* out = (float*)d_out;

    // harness re-poisons d_out to 0xAA before every timed launch
    hipMemsetAsync(d_out, 0, (size_t)out_size * sizeof(float), stream);

    dim3 grid(BATCH * (HH / TH));
    circle_mse_kernel<<<grid, NTHREADS, 0, stream>>>(y_pred, y_true, out);
}

// Round 4
// 169.065 us; speedup vs baseline: 1.3106x; 1.0754x over previous
//
#include <hip/hip_runtime.h>
#include <stdint.h>

#define BATCH 16
#define HH 1024
#define WW 1024
#define TH 8                  // output rows per block
#define HALO 4
#define ROWS (TH + 2*HALO)    // 16 staged rows
#define WORDS (WW/64)         // 16 uint64 words per row
#define NTHREADS 256
#define NWAVES (NTHREADS/64)
#define TOTAL_WORDS (BATCH * HH * WORDS)   // 262144 words = 2 MB packed

// ---------------- kernel 1: ballot-pack y_true into bit-plane ----------------
__global__ __launch_bounds__(NTHREADS) void pack_kernel(
    const float* __restrict__ y_true,
    unsigned long long* __restrict__ packed)
{
    const int lane = threadIdx.x & 63;
    const size_t base = ((size_t)((blockIdx.x * NTHREADS + threadIdx.x) >> 6)) * 64;
    unsigned long long mine = 0ull;
    #pragma unroll 16
    for (int i = 0; i < 64; ++i) {
        float v = y_true[(base + (size_t)i) * 64 + lane];
        unsigned long long m = __ballot(v != 0.0f);
        mine = (lane == i) ? m : mine;
    }
    packed[base + lane] = mine;   // 512 B coalesced per wave
}

// ---------------- kernel 2: erosion (bit ops in LDS) + fused weighted MSE ----
__global__ __launch_bounds__(NTHREADS) void erode_mse_kernel(
    const float* __restrict__ y_pred,
    const unsigned long long* __restrict__ packed,
    float* __restrict__ out)
{
    __shared__ unsigned long long bits0[ROWS][WORDS];  // packed y_true (kept)
    __shared__ unsigned long long bufA[ROWS][WORDS];   // erosion ping
    __shared__ unsigned long long bufB[ROWS][WORDS];   // erosion pong
    __shared__ unsigned long long E[4][TH][WORDS];     // e1..e4 central bit-planes
    __shared__ float wavesum[NWAVES];

    const int tid  = threadIdx.x;
    const int lane = tid & 63;
    const int wave = tid >> 6;

    const int im = blockIdx.x / (HH / TH);
    const int rb = blockIdx.x % (HH / TH);
    const int r0 = rb * TH - HALO;  // global row of staged row 0

    const float* yp = y_pred + (size_t)im * HH * WW;

    // ---- load packed tile: one uint64 per thread (ROWS*WORDS == NTHREADS) ----
    {
        int row  = tid >> 4;
        int word = tid & (WORDS - 1);
        int gr   = r0 + row;
        unsigned long long m = 0ull;
        if (gr >= 0 && gr < HH)
            m = packed[((size_t)im * HH + gr) * WORDS + word];
        bits0[row][word] = m;
        bufA[row][word]  = m;
    }
    __syncthreads();

    // ---- 4 merged 3x3 erosions (h+v in one pass), ping-pong, shrinking halo ----
    #pragma unroll
    for (int k = 1; k <= 4; ++k) {
        unsigned long long (*src)[WORDS] = (k & 1) ? bufA : bufB;
        unsigned long long (*dst)[WORDS] = (k & 1) ? bufB : bufA;
        int lo = k, hi = ROWS - k;
        int n  = (hi - lo) * WORDS;          // <= 224 <= 256: one item/thread
        if (tid < n) {
            int row  = lo + (tid >> 4);
            int word = tid & (WORDS - 1);
            unsigned long long h0, h1, h2;
            {
                unsigned long long m = src[row - 1][word];
                unsigned long long l = (word > 0)         ? src[row - 1][word - 1] : 0ull;
                unsigned long long r = (word < WORDS - 1) ? src[row - 1][word + 1] : 0ull;
                h0 = m & ((m << 1) | (l >> 63)) & ((m >> 1) | (r << 63));
            }
            {
                unsigned long long m = src[row][word];
                unsigned long long l = (word > 0)         ? src[row][word - 1] : 0ull;
                unsigned long long r = (word < WORDS - 1) ? src[row][word + 1] : 0ull;
                h1 = m & ((m << 1) | (l >> 63)) & ((m >> 1) | (r << 63));
            }
            {
                unsigned long long m = src[row + 1][word];
                unsigned long long l = (word > 0)         ? src[row + 1][word - 1] : 0ull;
                unsigned long long r = (word < WORDS - 1) ? src[row + 1][word + 1] : 0ull;
                h2 = m & ((m << 1) | (l >> 63)) & ((m >> 1) | (r << 63));
            }
            unsigned long long res = h0 & h1 & h2;
            dst[row][word] = res;
            if (row >= HALO && row < HALO + TH) E[k - 1][row - HALO][word] = res;
        }
        __syncthreads();
    }

    // ---- fused weighted-MSE + reduction (float4 y_pred loads) ----
    const int word = tid >> 4;          // (4*tid)/64
    const int bsh  = (tid & 15) * 4;    // bit position of column 4*tid within word
    float lsum = 0.0f;
    #pragma unroll
    for (int row = 0; row < TH; ++row) {
        int gr = r0 + HALO + row;
        float4 pv = *reinterpret_cast<const float4*>(&yp[(size_t)gr * WW + tid * 4]);
        unsigned int y4 = (unsigned int)((bits0[row + HALO][word] >> bsh) & 0xFull);
        unsigned int n1 = (unsigned int)((E[0][row][word] >> bsh) & 0xFull);
        unsigned int n2 = (unsigned int)((E[1][row][word] >> bsh) & 0xFull);
        unsigned int n3 = (unsigned int)((E[2][row][word] >> bsh) & 0xFull);
        unsigned int n4 = (unsigned int)((E[3][row][word] >> bsh) & 0xFull);
        float pvals[4] = {pv.x, pv.y, pv.z, pv.w};
        #pragma unroll
        for (int j = 0; j < 4; ++j) {
            unsigned int y = (y4 >> j) & 1u;
            unsigned int c = y + ((n1 >> j) & 1u) + ((n2 >> j) & 1u)
                               + ((n3 >> j) & 1u) + ((n4 >> j) & 1u);
            float w = (c == 0u || c == 5u) ? 0.8f : (0.3f + 0.1f * (float)c);
            float d = pvals[j] - (float)y;
            lsum += d * d * w;
        }
    }

    // wave reduce (64 lanes)
    for (int off = 32; off > 0; off >>= 1)
        lsum += __shfl_down(lsum, off, 64);
    if (lane == 0) wavesum[wave] = lsum;
    __syncthreads();
    if (tid == 0) {
        float s = 0.0f;
        for (int wv = 0; wv < NWAVES; ++wv) s += wavesum[wv];
        atomicAdd(&out[im], s * (1.0f / (float)(HH * WW)));
        atomicAdd(&out[BATCH], s * (1.0f / ((float)BATCH * (float)(HH * WW))));
    }
}

// ---------------- fallback: round-3 single-kernel path ----------------
__global__ __launch_bounds__(NTHREADS) void circle_mse_kernel(
    const float* __restrict__ y_pred,
    const float* __restrict__ y_true,
    float* __restrict__ out)
{
    __shared__ unsigned long long bits0[ROWS][WORDS];
    __shared__ unsigned long long cur[ROWS][WORDS];
    __shared__ unsigned long long tmp[ROWS][WORDS];
    __shared__ unsigned long long E[4][TH][WORDS];
    __shared__ float wavesum[NWAVES];

    const int tid  = threadIdx.x;
    const int lane = tid & 63;
    const int wave = tid >> 6;
    const int im = blockIdx.x / (HH / TH);
    const int rb = blockIdx.x % (HH / TH);
    const int r0 = rb * TH - HALO;
    const float* yt = y_true + (size_t)im * HH * WW;
    const float* yp = y_pred + (size_t)im * HH * WW;

    #pragma unroll 8
    for (int p = wave; p < ROWS * WORDS; p += NWAVES) {
        int row  = p >> 4;
        int word = p & (WORDS - 1);
        int gr   = r0 + row;
        unsigned long long m = 0ull;
        if (gr >= 0 && gr < HH) {
            float v = yt[(size_t)gr * WW + word * 64 + lane];
            m = __ballot(v != 0.0f);
        }
        if (lane == 0) { bits0[row][word] = m; cur[row][word] = m; }
    }
    __syncthreads();

    for (int k = 1; k <= 4; ++k) {
        int lo = k - 1, hi = ROWS - (k - 1);
        for (int p = tid; p < (hi - lo) * WORDS; p += NTHREADS) {
            int row  = lo + (p >> 4);
            int word = p & (WORDS - 1);
            unsigned long long m = cur[row][word];
            unsigned long long l = (word > 0)         ? cur[row][word - 1] : 0ull;
            unsigned long long r = (word < WORDS - 1) ? cur[row][word + 1] : 0ull;
            tmp[row][word] = m & ((m << 1) | (l >> 63)) & ((m >> 1) | (r << 63));
        }
        __syncthreads();
        lo = k; hi = ROWS - k;
        for (int p = tid; p < (hi - lo) * WORDS; p += NTHREADS) {
            int row  = lo + (p >> 4);
            int word = p & (WORDS - 1);
            unsigned long long res = tmp[row - 1][word] & tmp[row][word] & tmp[row + 1][word];
            cur[row][word] = res;
            if (row >= HALO && row < HALO + TH) E[k - 1][row - HALO][word] = res;
        }
        __syncthreads();
    }

    const int word = tid >> 4;
    const int bsh  = (tid & 15) * 4;
    float lsum = 0.0f;
    #pragma unroll
    for (int row = 0; row < TH; ++row) {
        int gr = r0 + HALO + row;
        float4 pv = *reinterpret_cast<const float4*>(&yp[(size_t)gr * WW + tid * 4]);
        unsigned int y4 = (unsigned int)((bits0[row + HALO][word] >> bsh) & 0xFull);
        unsigned int n1 = (unsigned int)((E[0][row][word] >> bsh) & 0xFull);
        unsigned int n2 = (unsigned int)((E[1][row][word] >> bsh) & 0xFull);
        unsigned int n3 = (unsigned int)((E[2][row][word] >> bsh) & 0xFull);
        unsigned int n4 = (unsigned int)((E[3][row][word] >> bsh) & 0xFull);
        float pvals[4] = {pv.x, pv.y, pv.z, pv.w};
        #pragma unroll
        for (int j = 0; j < 4; ++j) {
            unsigned int y = (y4 >> j) & 1u;
            unsigned int c = y + ((n1 >> j) & 1u) + ((n2 >> j) & 1u)
                               + ((n3 >> j) & 1u) + ((n4 >> j) & 1u);
            float w = (c == 0u || c == 5u) ? 0.8f : (0.3f + 0.1f * (float)c);
            float d = pvals[j] - (float)y;
            lsum += d * d * w;
        }
    }
    for (int off = 32; off > 0; off >>= 1)
        lsum += __shfl_down(lsum, off, 64);
    if (lane == 0) wavesum[wave] = lsum;
    __syncthreads();
    if (tid == 0) {
        float s = 0.0f;
        for (int wv = 0; wv < NWAVES; ++wv) s += wavesum[wv];
        atomicAdd(&out[im], s * (1.0f / (float)(HH * WW)));
        atomicAdd(&out[BATCH], s * (1.0f / ((float)BATCH * (float)(HH * WW))));
    }
}

extern "C" void kernel_launch(void* const* d_in, const int* in_sizes, int n_in,
                              void* d_out, int out_size, void* d_ws, size_t ws_size,
                              hipStream_t stream) {
    const float* y_pred = (const float*)d_in[0];
    const float* y_true = (const float*)d_in[1];
    float* out = (float*)d_out;

    // harness re-poisons d_out to 0xAA before every timed launch
    hipMemsetAsync(d_out, 0, (size_t)out_size * sizeof(float), stream);

    const size_t need = (size_t)TOTAL_WORDS * sizeof(unsigned long long); // 2 MB
    if (ws_size >= need && d_ws != nullptr) {
        unsigned long long* packed = (unsigned long long*)d_ws;
        // 262144 words / 64 per wave = 4096 waves = 1024 blocks
        pack_kernel<<<dim3(TOTAL_WORDS / 64 / NWAVES), NTHREADS, 0, stream>>>(y_true, packed);
        erode_mse_kernel<<<dim3(BATCH * (HH / TH)), NTHREADS, 0, stream>>>(y_pred, packed, out);
    } else {
        circle_mse_kernel<<<dim3(BATCH * (HH / TH)), NTHREADS, 0, stream>>>(y_pred, y_true, out);
    }
}

// Round 5
// 148.778 us; speedup vs baseline: 1.4893x; 1.1364x over previous
//
#include <hip/hip_runtime.h>
#include <stdint.h>

#define BATCH 16
#define HH 1024
#define WW 1024
#define TH 8                  // output rows per block
#define HALO 4
#define ROWS (TH + 2*HALO)    // 16 staged rows
#define WORDS (WW/64)         // 16 uint64 words per row
#define WPAD (WORDS + 1)      // padded inner dim: kills 4-way ds_read_b64 bank conflict
#define NTHREADS 256
#define NWAVES (NTHREADS/64)
#define TOTAL_WORDS (BATCH * HH * WORDS)   // 262144 words = 2 MB packed
#define NBLOCKS_MSE (BATCH * (HH / TH))    // 2048

// ---------------- kernel 1: ballot-pack y_true into bit-plane ----------------
// 32 words per wave => 8192 waves => 32 waves/CU (100% occupancy)
__global__ __launch_bounds__(NTHREADS) void pack_kernel(
    const float* __restrict__ y_true,
    unsigned long long* __restrict__ packed)
{
    const int lane = threadIdx.x & 63;
    const size_t base = ((size_t)((blockIdx.x * NTHREADS + threadIdx.x) >> 6)) * 32;
    unsigned long long mine = 0ull;
    #pragma unroll
    for (int i = 0; i < 32; ++i) {
        float v = y_true[(base + (size_t)i) * 64 + lane];
        unsigned long long m = __ballot(v != 0.0f);
        mine = (lane == i) ? m : mine;
    }
    if (lane < 32) packed[base + lane] = mine;   // 256 B coalesced per wave
}

// ---------------- kernel 2: erosion (bit ops in LDS) + fused weighted MSE ----
// Writes ONE partial sum per block into ws_partial[blockIdx] (no atomics).
__global__ __launch_bounds__(NTHREADS) void erode_mse_kernel(
    const float* __restrict__ y_pred,
    const unsigned long long* __restrict__ packed,
    float* __restrict__ ws_partial)
{
    __shared__ unsigned long long bits0[ROWS][WPAD];   // packed y_true (kept)
    __shared__ unsigned long long bufA[ROWS][WPAD];    // erosion ping
    __shared__ unsigned long long bufB[ROWS][WPAD];    // erosion pong
    __shared__ unsigned long long E[4][TH][WPAD];      // e1..e4 central bit-planes
    __shared__ float wavesum[NWAVES];

    const int tid  = threadIdx.x;
    const int lane = tid & 63;
    const int wave = tid >> 6;

    const int im = blockIdx.x / (HH / TH);
    const int rb = blockIdx.x % (HH / TH);
    const int r0 = rb * TH - HALO;  // global row of staged row 0

    const float* yp = y_pred + (size_t)im * HH * WW;

    // ---- load packed tile: one uint64 per thread (ROWS*WORDS == NTHREADS) ----
    {
        int row  = tid >> 4;
        int word = tid & (WORDS - 1);
        int gr   = r0 + row;
        unsigned long long m = 0ull;
        if (gr >= 0 && gr < HH)
            m = packed[((size_t)im * HH + gr) * WORDS + word];
        bits0[row][word] = m;
        bufA[row][word]  = m;
    }
    __syncthreads();

    // ---- 4 merged 3x3 erosions (h+v in one pass), ping-pong, shrinking halo ----
    #pragma unroll
    for (int k = 1; k <= 4; ++k) {
        unsigned long long (*src)[WPAD] = (k & 1) ? bufA : bufB;
        unsigned long long (*dst)[WPAD] = (k & 1) ? bufB : bufA;
        int lo = k, hi = ROWS - k;
        int n  = (hi - lo) * WORDS;          // <= 224 <= 256: one item/thread
        if (tid < n) {
            int row  = lo + (tid >> 4);
            int word = tid & (WORDS - 1);
            unsigned long long h0, h1, h2;
            {
                unsigned long long m = src[row - 1][word];
                unsigned long long l = (word > 0)         ? src[row - 1][word - 1] : 0ull;
                unsigned long long r = (word < WORDS - 1) ? src[row - 1][word + 1] : 0ull;
                h0 = m & ((m << 1) | (l >> 63)) & ((m >> 1) | (r << 63));
            }
            {
                unsigned long long m = src[row][word];
                unsigned long long l = (word > 0)         ? src[row][word - 1] : 0ull;
                unsigned long long r = (word < WORDS - 1) ? src[row][word + 1] : 0ull;
                h1 = m & ((m << 1) | (l >> 63)) & ((m >> 1) | (r << 63));
            }
            {
                unsigned long long m = src[row + 1][word];
                unsigned long long l = (word > 0)         ? src[row + 1][word - 1] : 0ull;
                unsigned long long r = (word < WORDS - 1) ? src[row + 1][word + 1] : 0ull;
                h2 = m & ((m << 1) | (l >> 63)) & ((m >> 1) | (r << 63));
            }
            unsigned long long res = h0 & h1 & h2;
            dst[row][word] = res;
            if (row >= HALO && row < HALO + TH) E[k - 1][row - HALO][word] = res;
        }
        __syncthreads();
    }

    // ---- fused weighted-MSE + reduction (float4 y_pred loads) ----
    const int word = tid >> 4;          // (4*tid)/64
    const int bsh  = (tid & 15) * 4;    // bit position of column 4*tid within word
    float lsum = 0.0f;
    #pragma unroll
    for (int row = 0; row < TH; ++row) {
        int gr = r0 + HALO + row;
        float4 pv = *reinterpret_cast<const float4*>(&yp[(size_t)gr * WW + tid * 4]);
        unsigned int y4 = (unsigned int)((bits0[row + HALO][word] >> bsh) & 0xFull);
        unsigned int n1 = (unsigned int)((E[0][row][word] >> bsh) & 0xFull);
        unsigned int n2 = (unsigned int)((E[1][row][word] >> bsh) & 0xFull);
        unsigned int n3 = (unsigned int)((E[2][row][word] >> bsh) & 0xFull);
        unsigned int n4 = (unsigned int)((E[3][row][word] >> bsh) & 0xFull);
        float pvals[4] = {pv.x, pv.y, pv.z, pv.w};
        #pragma unroll
        for (int j = 0; j < 4; ++j) {
            unsigned int y = (y4 >> j) & 1u;
            unsigned int c = y + ((n1 >> j) & 1u) + ((n2 >> j) & 1u)
                               + ((n3 >> j) & 1u) + ((n4 >> j) & 1u);
            float w = (c == 0u || c == 5u) ? 0.8f : (0.3f + 0.1f * (float)c);
            float d = pvals[j] - (float)y;
            lsum += d * d * w;
        }
    }

    // wave reduce (64 lanes)
    for (int off = 32; off > 0; off >>= 1)
        lsum += __shfl_down(lsum, off, 64);
    if (lane == 0) wavesum[wave] = lsum;
    __syncthreads();
    if (tid == 0) {
        float s = 0.0f;
        for (int wv = 0; wv < NWAVES; ++wv) s += wavesum[wv];
        ws_partial[blockIdx.x] = s;   // private slot — no atomic
    }
}

// ---------------- kernel 3: final reduction over 2048 block partials ----------
// partial layout: [im*128 + rb]; thread t sums partials [8t, 8t+8) (same image).
__global__ __launch_bounds__(NTHREADS) void reduce_kernel(
    const float* __restrict__ partial,
    float* __restrict__ out)
{
    __shared__ float ssum[NTHREADS];
    __shared__ float imsum[BATCH];
    const int tid = threadIdx.x;
    float s = 0.0f;
    #pragma unroll
    for (int j = 0; j < NBLOCKS_MSE / NTHREADS; ++j)
        s += partial[tid * (NBLOCKS_MSE / NTHREADS) + j];
    ssum[tid] = s;
    __syncthreads();
    if (tid < BATCH) {                      // 16 threads, one image each
        float a = 0.0f;
        #pragma unroll
        for (int t = 0; t < NTHREADS / BATCH; ++t)
            a += ssum[tid * (NTHREADS / BATCH) + t];
        imsum[tid] = a;
        out[tid] = a * (1.0f / (float)(HH * WW));
    }
    __syncthreads();
    if (tid == 0) {
        float tot = 0.0f;
        #pragma unroll
        for (int i = 0; i < BATCH; ++i) tot += imsum[i];
        out[BATCH] = tot * (1.0f / ((float)BATCH * (float)(HH * WW)));
    }
}

// ---------------- fallback: single-kernel path (atomics, needs memset) -------
__global__ __launch_bounds__(NTHREADS) void circle_mse_kernel(
    const float* __restrict__ y_pred,
    const float* __restrict__ y_true,
    float* __restrict__ out)
{
    __shared__ unsigned long long bits0[ROWS][WPAD];
    __shared__ unsigned long long cur[ROWS][WPAD];
    __shared__ unsigned long long tmp[ROWS][WPAD];
    __shared__ unsigned long long E[4][TH][WPAD];
    __shared__ float wavesum[NWAVES];

    const int tid  = threadIdx.x;
    const int lane = tid & 63;
    const int wave = tid >> 6;
    const int im = blockIdx.x / (HH / TH);
    const int rb = blockIdx.x % (HH / TH);
    const int r0 = rb * TH - HALO;
    const float* yt = y_true + (size_t)im * HH * WW;
    const float* yp = y_pred + (size_t)im * HH * WW;

    #pragma unroll 8
    for (int p = wave; p < ROWS * WORDS; p += NWAVES) {
        int row  = p >> 4;
        int word = p & (WORDS - 1);
        int gr   = r0 + row;
        unsigned long long m = 0ull;
        if (gr >= 0 && gr < HH) {
            float v = yt[(size_t)gr * WW + word * 64 + lane];
            m = __ballot(v != 0.0f);
        }
        if (lane == 0) { bits0[row][word] = m; cur[row][word] = m; }
    }
    __syncthreads();

    for (int k = 1; k <= 4; ++k) {
        int lo = k - 1, hi = ROWS - (k - 1);
        for (int p = tid; p < (hi - lo) * WORDS; p += NTHREADS) {
            int row  = lo + (p >> 4);
            int word = p & (WORDS - 1);
            unsigned long long m = cur[row][word];
            unsigned long long l = (word > 0)         ? cur[row][word - 1] : 0ull;
            unsigned long long r = (word < WORDS - 1) ? cur[row][word + 1] : 0ull;
            tmp[row][word] = m & ((m << 1) | (l >> 63)) & ((m >> 1) | (r << 63));
        }
        __syncthreads();
        lo = k; hi = ROWS - k;
        for (int p = tid; p < (hi - lo) * WORDS; p += NTHREADS) {
            int row  = lo + (p >> 4);
            int word = p & (WORDS - 1);
            unsigned long long res = tmp[row - 1][word] & tmp[row][word] & tmp[row + 1][word];
            cur[row][word] = res;
            if (row >= HALO && row < HALO + TH) E[k - 1][row - HALO][word] = res;
        }
        __syncthreads();
    }

    const int word = tid >> 4;
    const int bsh  = (tid & 15) * 4;
    float lsum = 0.0f;
    #pragma unroll
    for (int row = 0; row < TH; ++row) {
        int gr = r0 + HALO + row;
        float4 pv = *reinterpret_cast<const float4*>(&yp[(size_t)gr * WW + tid * 4]);
        unsigned int y4 = (unsigned int)((bits0[row + HALO][word] >> bsh) & 0xFull);
        unsigned int n1 = (unsigned int)((E[0][row][word] >> bsh) & 0xFull);
        unsigned int n2 = (unsigned int)((E[1][row][word] >> bsh) & 0xFull);
        unsigned int n3 = (unsigned int)((E[2][row][word] >> bsh) & 0xFull);
        unsigned int n4 = (unsigned int)((E[3][row][word] >> bsh) & 0xFull);
        float pvals[4] = {pv.x, pv.y, pv.z, pv.w};
        #pragma unroll
        for (int j = 0; j < 4; ++j) {
            unsigned int y = (y4 >> j) & 1u;
            unsigned int c = y + ((n1 >> j) & 1u) + ((n2 >> j) & 1u)
                               + ((n3 >> j) & 1u) + ((n4 >> j) & 1u);
            float w = (c == 0u || c == 5u) ? 0.8f : (0.3f + 0.1f * (float)c);
            float d = pvals[j] - (float)y;
            lsum += d * d * w;
        }
    }
    for (int off = 32; off > 0; off >>= 1)
        lsum += __shfl_down(lsum, off, 64);
    if (lane == 0) wavesum[wave] = lsum;
    __syncthreads();
    if (tid == 0) {
        float s = 0.0f;
        for (int wv = 0; wv < NWAVES; ++wv) s += wavesum[wv];
        atomicAdd(&out[im], s * (1.0f / (float)(HH * WW)));
        atomicAdd(&out[BATCH], s * (1.0f / ((float)BATCH * (float)(HH * WW))));
    }
}

extern "C" void kernel_launch(void* const* d_in, const int* in_sizes, int n_in,
                              void* d_out, int out_size, void* d_ws, size_t ws_size,
                              hipStream_t stream) {
    const float* y_pred = (const float*)d_in[0];
    const float* y_true = (const float*)d_in[1];
    float* out = (float*)d_out;

    const size_t need = (size_t)TOTAL_WORDS * sizeof(unsigned long long)
                      + (size_t)NBLOCKS_MSE * sizeof(float);   // 2 MB + 8 KB
    if (ws_size >= need && d_ws != nullptr) {
        unsigned long long* packed = (unsigned long long*)d_ws;
        float* ws_partial = (float*)(packed + TOTAL_WORDS);
        // 262144 words / 32 per wave / 4 waves per block = 2048 blocks
        pack_kernel<<<dim3(TOTAL_WORDS / 32 / NWAVES), NTHREADS, 0, stream>>>(y_true, packed);
        erode_mse_kernel<<<dim3(NBLOCKS_MSE), NTHREADS, 0, stream>>>(y_pred, packed, ws_partial);
        reduce_kernel<<<dim3(1), NTHREADS, 0, stream>>>(ws_partial, out);
    } else {
        hipMemsetAsync(d_out, 0, (size_t)out_size * sizeof(float), stream);
        circle_mse_kernel<<<dim3(NBLOCKS_MSE), NTHREADS, 0, stream>>>(y_pred, y_true, out);
    }
}